// Round 1
// baseline (267.093 us; speedup 1.0000x reference)
//
#include <hip/hip_runtime.h>

#define BB 32
#define HH 56
#define WW 56
#define CC 256
#define PSTRIP 4
#define STRIPS_PER_ROW (WW / PSTRIP)   // 14

__device__ __forceinline__ void load8(const float* __restrict__ p, float v[8]) {
    float4 a = *reinterpret_cast<const float4*>(p);
    float4 b = *reinterpret_cast<const float4*>(p + 4);
    v[0]=a.x; v[1]=a.y; v[2]=a.z; v[3]=a.w;
    v[4]=b.x; v[5]=b.y; v[6]=b.z; v[7]=b.w;
}

// thread = (group g of 8 channels, strip of PSTRIP pixels along W)
// lanes 0..31 = the 32 groups of one pixel -> contiguous 1KB coalesced rows.
// weights (8x8 gamma_k slice + 8 masked gamma_s taps) live in registers,
// amortized over the strip. Neighbor x reads rely on L1/L2 (NHWC rows are
// 57KB; L2 per XCD 4MB holds ~70 rows).
__global__ __launch_bounds__(256, 2) void dn_kernel(
    const float* __restrict__ x,
    const float* __restrict__ gk_g,
    const float* __restrict__ gs_g,
    const float* __restrict__ beta,
    const float* __restrict__ beta_o,
    const float* __restrict__ gamma_o,
    const int* __restrict__ sdist,
    float* __restrict__ out)
{
    const int d   = sdist[0];                 // surround_dist (uniform scalar)
    const int tid = blockIdx.x * 256 + threadIdx.x;
    const int g   = tid & 31;
    const int s   = tid >> 5;
    const int sw  = s % STRIPS_PER_ROW;
    const int t1  = s / STRIPS_PER_ROW;
    const int h   = t1 % HH;
    const int b   = t1 / HH;
    const int w0  = sw * PSTRIP;
    const int c0  = g << 3;

    // gamma_k[0,0].reshape(8,G,8): w[i][g][o] = gk_g[i*CC + g*8 + o]
    float gk[8][8];
#pragma unroll
    for (int i = 0; i < 8; ++i) load8(gk_g + i*CC + c0, gk[i]);

    // gamma_s (3,3,C,1), center tap (1,1) masked out -> 8 taps
    const int tap_kh[8] = {0,0,0,1,1,2,2,2};
    const int tap_kw[8] = {0,1,2,0,2,0,1,2};
    float gs[8][8];
#pragma unroll
    for (int t = 0; t < 8; ++t)
        load8(gs_g + (tap_kh[t]*3 + tap_kw[t])*CC + c0, gs[t]);

    float betav[8], gov[8], bov[8];
    load8(beta    + c0, betav);
    load8(gamma_o + c0, gov);
    load8(beta_o  + c0, bov);
#pragma unroll
    for (int o = 0; o < 8; ++o) betav[o] += 1e-6f;   // BETA_MIN

    const float* xrow = x   + (size_t)((b*HH + h)*WW)*CC;
    float*       orow = out + (size_t)((b*HH + h)*WW)*CC;

#pragma unroll
    for (int j = 0; j < PSTRIP; ++j) {
        const int w = w0 + j;

        float cx[8];
        load8(xrow + w*CC + c0, cx);

        float acc[8];
#pragma unroll
        for (int o = 0; o < 8; ++o) acc[o] = betav[o];

        // Pk: 8x8 per-group mix of x^2
#pragma unroll
        for (int i = 0; i < 8; ++i) {
            const float x2 = cx[i]*cx[i];
#pragma unroll
            for (int o = 0; o < 8; ++o) acc[o] += x2 * gk[i][o];
        }

        // Ps: 8 masked depthwise taps on x^2 (dilation d, zero padding)
#pragma unroll
        for (int t = 0; t < 8; ++t) {
            const int hh = h + (tap_kh[t]-1)*d;
            const int w2 = w + (tap_kw[t]-1)*d;
            if (hh >= 0 && hh < HH && w2 >= 0 && w2 < WW) {
                float xn[8];
                load8(x + (size_t)((b*HH + hh)*WW + w2)*CC + c0, xn);
#pragma unroll
                for (int o = 0; o < 8; ++o) acc[o] += (xn[o]*xn[o]) * gs[t][o];
            }
        }

        float res[8];
#pragma unroll
        for (int o = 0; o < 8; ++o) {
            const float np = __builtin_amdgcn_rsqf(acc[o]);   // v_rsq_f32
            res[o] = cx[o] * np * gov[o] + bov[o];
        }
        float4* op = reinterpret_cast<float4*>(orow + w*CC + c0);
        op[0] = make_float4(res[0], res[1], res[2], res[3]);
        op[1] = make_float4(res[4], res[5], res[6], res[7]);
    }
}

extern "C" void kernel_launch(void* const* d_in, const int* in_sizes, int n_in,
                              void* d_out, int out_size, void* d_ws, size_t ws_size,
                              hipStream_t stream) {
    const float* x       = (const float*)d_in[0];
    const float* gamma_k = (const float*)d_in[1];
    const float* gamma_s = (const float*)d_in[2];
    const float* beta    = (const float*)d_in[3];
    const float* beta_o  = (const float*)d_in[4];
    const float* gamma_o = (const float*)d_in[5];
    const int*   sdist   = (const int*)d_in[6];
    float* out = (float*)d_out;

    // threads = B*H*(W/PSTRIP)*32 groups = 32*56*14*32 = 802816 -> 3136 blocks
    const int total  = BB * HH * STRIPS_PER_ROW * 32;
    const int blocks = total / 256;
    dn_kernel<<<blocks, 256, 0, stream>>>(x, gamma_k, gamma_s, beta,
                                          beta_o, gamma_o, sdist, out);
}